// Round 2
// baseline (7063.317 us; speedup 1.0000x reference)
//
#include <hip/hip_runtime.h>
#include <hip/hip_bf16.h>
#include <stdint.h>

// ContainedLSTM: B=128, S=1024, I=256, H=256.
// Split-precision (Ootomo 2-term bf16) everywhere: v = v_hi + v_lo, product
// hi*hi + hi*lo + lo*hi with fp32 MFMA accumulation -> fp32-grade matmuls.
// Phase 1: xw[b,t,g] = x@W_ih^T  (split bf16 MFMA GEMM, chunked into ws)
// Phase 2: sequential recurrence, 32 WGs = 8 batch-groups x 4 j-slices.
//   LN folded:  gates = rs*(Wtil h) - rs*mu*R + D + xw,  Wtil = W_hh*gamma.
//   Each WG parks its W-quarter hi+lo (256KB bf16) in VGPRs.
//   Per-step inter-WG h-slice exchange (fp32) via device-scope flags.

#define Bb 128
#define Ss 1024
#define Ii 256
#define Hh 256
#define G4v 1024
#define EPSF 1e-5f

typedef __bf16 bf16;
typedef __attribute__((ext_vector_type(8))) __bf16 bf16x8;
typedef __attribute__((ext_vector_type(4))) __bf16 bf16x4;
typedef __attribute__((ext_vector_type(4))) float f32x4;

static __device__ __forceinline__ f32x4 mfma16(bf16x8 a, bf16x8 b, f32x4 c) {
  return __builtin_amdgcn_mfma_f32_16x16x32_bf16(a, b, c, 0, 0, 0);
}
static __device__ __forceinline__ float sigm(float x) { return 1.0f / (1.0f + __expf(-x)); }
static __device__ __forceinline__ float tanhf_(float x) {
  float e = __expf(-2.0f * fabsf(x));
  float t = (1.0f - e) / (1.0f + e);
  return x < 0.0f ? -t : t;
}

// ---------------- prep kernels ----------------
__global__ void k_conv_wih(const float* __restrict__ W, bf16* __restrict__ hi,
                           bf16* __restrict__ lo) {
  int i = (blockIdx.x * 256 + threadIdx.x) * 4;
  f32x4 v = *(const f32x4*)(W + i);
  bf16x4 h_, l_;
#pragma unroll
  for (int j = 0; j < 4; ++j) {
    bf16 hh = (bf16)v[j];
    h_[j] = hh;
    l_[j] = (bf16)(v[j] - (float)hh);
  }
  *(bf16x4*)(hi + i) = h_;
  *(bf16x4*)(lo + i) = l_;
}

// Wtil = W_hh * gamma, fragment-linear: Wf[(ntg*8+kt)*64 + lane][8] holds
// B-frag elem: Wtil[g = ntg*16 + (lane&15)][k = kt*32 + (lane>>4)*8 + j]
__global__ void k_prep_whh(const float* __restrict__ W, const float* __restrict__ gamma,
                           bf16* __restrict__ Whi, bf16* __restrict__ Wlo) {
  int tid = blockIdx.x * 256 + threadIdx.x;  // 0..32767
  int lane = tid & 63;
  int fk = tid >> 6;
  int ntg = fk >> 3, kt = fk & 7;
  int g = ntg * 16 + (lane & 15);
  int k = kt * 32 + ((lane >> 4) << 3);
  bf16x8 rh, rl;
#pragma unroll
  for (int j = 0; j < 8; ++j) {
    float wv = W[g * Hh + k + j] * gamma[k + j];
    bf16 hh = (bf16)wv;
    rh[j] = hh;
    rl[j] = (bf16)(wv - (float)hh);
  }
  *(bf16x8*)(Whi + (size_t)tid * 8) = rh;
  *(bf16x8*)(Wlo + (size_t)tid * 8) = rl;
}

__global__ void k_prep_rd(const float* __restrict__ W, const float* __restrict__ gamma,
                          const float* __restrict__ beta, const float* __restrict__ bih,
                          const float* __restrict__ bhh, float* __restrict__ RD) {
  int g = blockIdx.x * 256 + threadIdx.x;  // 1024 total
  float r = 0.f, d = 0.f;
  for (int k = 0; k < Hh; ++k) {
    float w = W[g * Hh + k];
    r += w * gamma[k];
    d += w * beta[k];
  }
  RD[2 * g] = r;
  RD[2 * g + 1] = d + bih[g] + bhh[g];
}

// ---------------- xw GEMM (split precision) ----------------
// grid: bid = (gt*ntb + tb)*128 + b; block 256 thr; 128 t-rows x 128 g-cols.
// B-panel hi+lo staged in LDS (64KB), two K-phases of 128.
__global__ __launch_bounds__(256, 2) void k_gemm(const float* __restrict__ x,
                                                 const bf16* __restrict__ Whi,
                                                 const bf16* __restrict__ Wlo,
                                                 float* __restrict__ xw,
                                                 int t0, int Tc, int ntb) {
  __shared__ bf16 Bs[2][128 * 128];  // [plane][row*128+col], rows XOR-swizzled
  int bid = blockIdx.x;
  int b = bid & 127;
  int r2 = bid >> 7;
  int tb = r2 % ntb;
  int gt = r2 / ntb;
  int g0 = gt * 128;
  int tid = threadIdx.x, w = tid >> 6, lane = tid & 63;
  int li = lane & 15, lg = lane >> 4;
  char* BsB = (char*)Bs;
  int tbase = tb * 128 + 32 * w;
  f32x4 acc[2][8];
#pragma unroll
  for (int mt = 0; mt < 2; ++mt)
#pragma unroll
    for (int nt = 0; nt < 8; ++nt) acc[mt][nt] = (f32x4){0.f, 0.f, 0.f, 0.f};

  for (int kp = 0; kp < 2; ++kp) {
    // stage both planes (row = g, 128 cols of k)
#pragma unroll
    for (int it = 0; it < 8; ++it) {
      int p = it * 4096 + tid * 16;  // bytes within 32KB plane
      int row = p >> 8, colb = p & 255;
      size_t goff = (size_t)(g0 + row) * 512 + kp * 256 + colb;
      int dst = row * 256 + (colb ^ ((row & 7) << 4));
      *(bf16x8*)(BsB + dst) = *(const bf16x8*)((const char*)Whi + goff);
      *(bf16x8*)(BsB + 32768 + dst) = *(const bf16x8*)((const char*)Wlo + goff);
    }
    __syncthreads();
#pragma unroll
    for (int kt = 0; kt < 4; ++kt) {
      int kl = kt * 32 + lg * 8;   // k within this 128-phase
      int kgl = kp * 128 + kl;     // global k
      bf16x8 ah[2], al[2];
#pragma unroll
      for (int mt = 0; mt < 2; ++mt) {
        int t = t0 + tbase + 16 * mt + li;
        const float* xp = x + ((size_t)b * Ss + t) * Ii + kgl;
        f32x4 f0 = *(const f32x4*)xp;
        f32x4 f1 = *(const f32x4*)(xp + 4);
        bf16x8 hv, lv;
#pragma unroll
        for (int j = 0; j < 4; ++j) {
          bf16 h0 = (bf16)f0[j];
          hv[j] = h0;
          lv[j] = (bf16)(f0[j] - (float)h0);
          bf16 h1 = (bf16)f1[j];
          hv[4 + j] = h1;
          lv[4 + j] = (bf16)(f1[j] - (float)h1);
        }
        ah[mt] = hv;
        al[mt] = lv;
      }
#pragma unroll
      for (int nt = 0; nt < 8; ++nt) {
        int grow = nt * 16 + li;
        int off = grow * 256 + ((kl * 2) ^ ((grow & 7) << 4));
        bf16x8 bh = *(const bf16x8*)(BsB + off);
        bf16x8 bl = *(const bf16x8*)(BsB + 32768 + off);
#pragma unroll
        for (int mt = 0; mt < 2; ++mt) {
          acc[mt][nt] = mfma16(ah[mt], bh, acc[mt][nt]);
          acc[mt][nt] = mfma16(ah[mt], bl, acc[mt][nt]);
          acc[mt][nt] = mfma16(al[mt], bh, acc[mt][nt]);
        }
      }
    }
    __syncthreads();
  }
#pragma unroll
  for (int mt = 0; mt < 2; ++mt)
#pragma unroll
    for (int nt = 0; nt < 8; ++nt)
#pragma unroll
      for (int r = 0; r < 4; ++r) {
        int tl = tbase + 16 * mt + lg * 4 + r;
        int g = g0 + nt * 16 + li;
        xw[((size_t)b * Tc + tl) * G4v + g] = acc[mt][nt][r];
      }
}

// ---------------- recurrence ----------------
// grid: 32 blocks, bid = q*8 + grp; block 256 thr / 4 waves.
__global__ __launch_bounds__(256, 1) void k_recur(
    const bf16* __restrict__ Whi_f, const bf16* __restrict__ Wlo_f,
    const float* __restrict__ xw, const int* __restrict__ mask,
    const float* __restrict__ RD, float* __restrict__ st_h, float* __restrict__ st_c,
    float* __restrict__ st_o, float* __restrict__ pub_h, int* __restrict__ flags,
    float* __restrict__ out, int t0, int Tc, int first, int last) {
  __shared__ bf16 hb[2][16 * 256];  // h hi/lo planes, byte ^= (row&7)<<4 swizzle
  __shared__ float murs[16][2];     // (mu*rs, rs) per batch row
  __shared__ float spart[16][16][2];
  int bid = blockIdx.x;
  int grp = bid & 7, q = bid >> 3;
  int tid = threadIdx.x, w = tid >> 6, lane = tid & 63;
  int li = lane & 15, lg = lane >> 4;
  int b0 = grp * 16;
  int jloc = (q * 4 + w) * 16 + li;
  char* hbB = (char*)hb;

  // park this wave's W-quarter (hi+lo) in VGPRs
  bf16x8 wph[4][8], wpl[4][8];
#pragma unroll
  for (int c = 0; c < 4; ++c)
#pragma unroll
    for (int kt = 0; kt < 8; ++kt) {
      int ntg = c * 16 + q * 4 + w;
      size_t off = ((size_t)(ntg * 8 + kt) * 64 + lane) * 8;
      wph[c][kt] = *(const bf16x8*)(Whi_f + off);
      wpl[c][kt] = *(const bf16x8*)(Wlo_f + off);
    }
  float Rr[4], Dd[4];
#pragma unroll
  for (int c = 0; c < 4; ++c) {
    int g = c * 256 + jloc;
    Rr[c] = RD[2 * g];
    Dd[c] = RD[2 * g + 1];
  }

  float cst[4], ost[4];
  if (first) {
#pragma unroll
    for (int i = 0; i < 16; ++i) {
      hb[0][tid * 16 + i] = (bf16)0.0f;
      hb[1][tid * 16 + i] = (bf16)0.0f;
    }
#pragma unroll
    for (int r = 0; r < 4; ++r) { cst[r] = 0.f; ost[r] = 0.f; }
    if (tid < 16) { murs[tid][0] = 0.f; murs[tid][1] = rsqrtf(EPSF); }
  } else {
    int row = tid >> 4, jseg = (tid & 15) * 16;
    float s = 0.f, ss = 0.f;
#pragma unroll
    for (int i = 0; i < 16; ++i) {
      float v = st_h[(size_t)(b0 + row) * Hh + jseg + i];
      s += v;
      ss += v * v;
      bf16 hh = (bf16)v;
      int boff = row * 512 + (((jseg + i) * 2) ^ ((row & 7) << 4));
      *(bf16*)(hbB + boff) = hh;
      *(bf16*)(hbB + 8192 + boff) = (bf16)(v - (float)hh);
    }
    spart[row][tid & 15][0] = s;
    spart[row][tid & 15][1] = ss;
#pragma unroll
    for (int r = 0; r < 4; ++r) {
      int m = lg * 4 + r;
      cst[r] = st_c[(size_t)(b0 + m) * Hh + jloc];
      ost[r] = st_o[(size_t)(b0 + m) * Hh + jloc];
    }
    __syncthreads();
    if (tid < 16) {
      float s2 = 0.f, ss2 = 0.f;
#pragma unroll
      for (int i = 0; i < 16; ++i) { s2 += spart[tid][i][0]; ss2 += spart[tid][i][1]; }
      float mu = s2 * (1.f / 256.f);
      float var = ss2 * (1.f / 256.f) - mu * mu;
      float rs = rsqrtf(var + EPSF);
      murs[tid][0] = mu * rs;
      murs[tid][1] = rs;
    }
  }
  __syncthreads();

  // preload xw/mask for tl=0
  float xwv[4][4];
  int mk[4];
#pragma unroll
  for (int c = 0; c < 4; ++c)
#pragma unroll
    for (int r = 0; r < 4; ++r)
      xwv[c][r] = xw[((size_t)(b0 + lg * 4 + r) * Tc + 0) * G4v + c * 256 + jloc];
#pragma unroll
  for (int r = 0; r < 4; ++r) mk[r] = mask[(size_t)(b0 + lg * 4 + r) * Ss + t0];

  for (int tl = 0; tl < Tc; ++tl) {
    int tg = t0 + tl;
    int tln = (tl + 1 < Tc) ? tl + 1 : Tc - 1;
    float xwn[4][4];
    int mkn[4];
#pragma unroll
    for (int c = 0; c < 4; ++c)
#pragma unroll
      for (int r = 0; r < 4; ++r)
        xwn[c][r] = xw[((size_t)(b0 + lg * 4 + r) * Tc + tln) * G4v + c * 256 + jloc];
#pragma unroll
    for (int r = 0; r < 4; ++r) mkn[r] = mask[(size_t)(b0 + lg * 4 + r) * Ss + t0 + tln];

    // P1: split MFMA  gates_acc = Wtil * h
    f32x4 acc[4];
#pragma unroll
    for (int c = 0; c < 4; ++c) acc[c] = (f32x4){0.f, 0.f, 0.f, 0.f};
#pragma unroll
    for (int kt = 0; kt < 8; ++kt) {
      int kk = kt * 32 + lg * 8;
      int aoff = li * 512 + ((kk * 2) ^ ((li & 7) << 4));
      bf16x8 ah = *(const bf16x8*)(hbB + aoff);
      bf16x8 al = *(const bf16x8*)(hbB + 8192 + aoff);
#pragma unroll
      for (int c = 0; c < 4; ++c) {
        acc[c] = mfma16(ah, wph[c][kt], acc[c]);
        acc[c] = mfma16(ah, wpl[c][kt], acc[c]);
        acc[c] = mfma16(al, wph[c][kt], acc[c]);
      }
    }
    float mrs[4], rsv[4];
#pragma unroll
    for (int r = 0; r < 4; ++r) {
      int m = lg * 4 + r;
      mrs[r] = murs[m][0];
      rsv[r] = murs[m][1];
    }
    __syncthreads();  // SYNC_A

    // P2: gates -> c,h,out; write own h-slice (LDS planes + fp32 publish)
    float hnew[4];
#pragma unroll
    for (int r = 0; r < 4; ++r) {
      float i_ = acc[0][r] * rsv[r] - mrs[r] * Rr[0] + Dd[0] + xwv[0][r];
      float f_ = acc[1][r] * rsv[r] - mrs[r] * Rr[1] + Dd[1] + xwv[1][r];
      float g_ = acc[2][r] * rsv[r] - mrs[r] * Rr[2] + Dd[2] + xwv[2][r];
      float o_ = acc[3][r] * rsv[r] - mrs[r] * Rr[3] + Dd[3] + xwv[3][r];
      float cn = sigm(f_) * cst[r] + sigm(i_) * tanhf_(g_);
      float hn = sigm(o_) * tanhf_(cn);
      cst[r] = cn;
      ost[r] = mk[r] ? ost[r] : hn;
      hnew[r] = hn;
    }
    int slot = (tg + 1) & 1;
    float* ph = pub_h + (size_t)(slot * 32 + bid) * 1024;
#pragma unroll
    for (int r = 0; r < 4; ++r) {
      int m = lg * 4 + r;
      float hn = hnew[r];
      bf16 hh = (bf16)hn;
      int boff = m * 512 + ((jloc * 2) ^ ((m & 7) << 4));
      *(bf16*)(hbB + boff) = hh;
      *(bf16*)(hbB + 8192 + boff) = (bf16)(hn - (float)hh);
      ph[m * 64 + (w * 16 + li)] = hn;
    }
    if (last && tl == Tc - 1) {
#pragma unroll
      for (int r = 0; r < 4; ++r) out[(size_t)(b0 + lg * 4 + r) * Hh + jloc] = ost[r];
    }
    if (tl == Tc - 1) {
#pragma unroll
      for (int r = 0; r < 4; ++r) {
        int m = lg * 4 + r;
        st_h[(size_t)(b0 + m) * Hh + jloc] = hnew[r];
        st_c[(size_t)(b0 + m) * Hh + jloc] = cst[r];
        st_o[(size_t)(b0 + m) * Hh + jloc] = ost[r];
      }
    }
#pragma unroll
    for (int c = 0; c < 4; ++c)
#pragma unroll
      for (int r = 0; r < 4; ++r) xwv[c][r] = xwn[c][r];
#pragma unroll
    for (int r = 0; r < 4; ++r) mk[r] = mkn[r];

    __threadfence();
    __syncthreads();  // SYNC_B
    if (tid == 0)
      __hip_atomic_store(&flags[bid], tg + 1, __ATOMIC_RELEASE, __HIP_MEMORY_SCOPE_AGENT);
    if (tid >= 1 && tid <= 3) {
      int qq = (q + tid) & 3;
      int pbid = qq * 8 + grp;
      int cnt = 0;
      while (__hip_atomic_load(&flags[pbid], __ATOMIC_ACQUIRE, __HIP_MEMORY_SCOPE_AGENT) <
             tg + 1) {
        if (++cnt > (1 << 22)) break;  // hang insurance
      }
    }
    __syncthreads();  // SYNC_C

    // P3: gather 3 partner fp32 slices, split into planes
#pragma unroll
    for (int pi = 1; pi < 4; ++pi) {
      int qq = (q + pi) & 3;
      int pbid = qq * 8 + grp;
      const float* src = pub_h + (size_t)(slot * 32 + pbid) * 1024;
      int idx = tid * 4;
      int row = idx >> 6, jj = idx & 63;
      f32x4 v = *(const f32x4*)(src + idx);
      bf16x4 h4, l4;
#pragma unroll
      for (int e = 0; e < 4; ++e) {
        bf16 hh = (bf16)v[e];
        h4[e] = hh;
        l4[e] = (bf16)(v[e] - (float)hh);
      }
      int boff = row * 512 + (((qq * 64 + jj) * 2) ^ ((row & 7) << 4));
      *(bf16x4*)(hbB + boff) = h4;
      *(bf16x4*)(hbB + 8192 + boff) = l4;
    }
    __syncthreads();  // SYNC_D
    // stats for next step's LN scalars (from hi+lo = fp32-exact h)
    {
      int row = tid >> 4, cs = tid & 15;
      float s = 0.f, ss = 0.f;
#pragma unroll
      for (int hseg = 0; hseg < 2; ++hseg) {
        int boff = row * 512 + (((cs * 16 + hseg * 8) * 2) ^ ((row & 7) << 4));
        bf16x8 vh = *(const bf16x8*)(hbB + boff);
        bf16x8 vl = *(const bf16x8*)(hbB + 8192 + boff);
#pragma unroll
        for (int j2 = 0; j2 < 8; ++j2) {
          float f = (float)vh[j2] + (float)vl[j2];
          s += f;
          ss += f * f;
        }
      }
      spart[row][cs][0] = s;
      spart[row][cs][1] = ss;
    }
    __syncthreads();  // SYNC_E
    if (tid < 16) {
      float s2 = 0.f, ss2 = 0.f;
#pragma unroll
      for (int i = 0; i < 16; ++i) { s2 += spart[tid][i][0]; ss2 += spart[tid][i][1]; }
      float mu = s2 * (1.f / 256.f);
      float var = ss2 * (1.f / 256.f) - mu * mu;
      float rs = rsqrtf(var + EPSF);
      murs[tid][0] = mu * rs;
      murs[tid][1] = rs;
    }
    __syncthreads();  // SYNC_F
  }
}

// ---------------- host ----------------
extern "C" void kernel_launch(void* const* d_in, const int* in_sizes, int n_in,
                              void* d_out, int out_size, void* d_ws, size_t ws_size,
                              hipStream_t stream) {
  (void)in_sizes; (void)n_in; (void)out_size;
  const float* x = (const float*)d_in[0];
  const int* mask = (const int*)d_in[1];
  const float* Wih = (const float*)d_in[2];
  const float* Whh = (const float*)d_in[3];
  const float* bih = (const float*)d_in[4];
  const float* bhh = (const float*)d_in[5];
  const float* gamma = (const float*)d_in[6];
  const float* beta = (const float*)d_in[7];
  float* outp = (float*)d_out;
  char* ws = (char*)d_ws;

  const size_t extra = 4 * (512u << 10) + (8u << 10) + 3 * (128u << 10) +
                       (256u << 10) + (64u << 10);
  int Tc = 128;
  if (ws_size >= (size_t)1024 * 524288 + extra) Tc = 1024;
  else if (ws_size >= (size_t)512 * 524288 + extra) Tc = 512;
  else if (ws_size >= (size_t)256 * 524288 + extra) Tc = 256;

  size_t o = 0;
  auto take = [&](size_t bytes) { size_t r = o; o += (bytes + 255) & ~(size_t)255; return r; };
  size_t xw_off = take((size_t)Bb * Tc * G4v * 4);
  size_t wihh_off = take(512u << 10);
  size_t wihl_off = take(512u << 10);
  size_t whhh_off = take(512u << 10);
  size_t whhl_off = take(512u << 10);
  size_t rd_off = take(8u << 10);
  size_t sth_off = take(128u << 10);
  size_t stc_off = take(128u << 10);
  size_t sto_off = take(128u << 10);
  size_t pub_off = take(256u << 10);
  size_t flg_off = take(256);

  bf16* wihh = (bf16*)(ws + wihh_off);
  bf16* wihl = (bf16*)(ws + wihl_off);
  bf16* whhh = (bf16*)(ws + whhh_off);
  bf16* whhl = (bf16*)(ws + whhl_off);
  float* rd = (float*)(ws + rd_off);
  float* xwp = (float*)(ws + xw_off);
  float* sth = (float*)(ws + sth_off);
  float* stc = (float*)(ws + stc_off);
  float* sto = (float*)(ws + sto_off);
  float* pubh = (float*)(ws + pub_off);
  int* flg = (int*)(ws + flg_off);

  hipMemsetAsync(flg, 0, 256, stream);
  k_conv_wih<<<dim3(256), dim3(256), 0, stream>>>(Wih, wihh, wihl);
  k_prep_whh<<<dim3(128), dim3(256), 0, stream>>>(Whh, gamma, whhh, whhl);
  k_prep_rd<<<dim3(4), dim3(256), 0, stream>>>(Whh, gamma, beta, bih, bhh, rd);

  int nchunk = Ss / Tc;
  int ntb = Tc / 128;
  for (int ci = 0; ci < nchunk; ++ci) {
    int t0 = ci * Tc;
    k_gemm<<<dim3(8 * ntb * 128), dim3(256), 0, stream>>>(x, wihh, wihl, xwp, t0, Tc, ntb);
    k_recur<<<dim3(32), dim3(256), 0, stream>>>(whhh, whhl, xwp, mask, rd, sth, stc, sto,
                                                pubh, flg, outp, t0, Tc,
                                                ci == 0 ? 1 : 0, ci == nchunk - 1 ? 1 : 0);
  }
}

// Round 3
// 5260.067 us; speedup vs baseline: 1.3428x; 1.3428x over previous
//
#include <hip/hip_runtime.h>
#include <hip/hip_bf16.h>
#include <stdint.h>

// ContainedLSTM: B=128, S=1024, I=256, H=256.
// Split-precision (Ootomo 2-term bf16): v = v_hi + v_lo, product
// hi*hi + hi*lo + lo*hi with fp32 MFMA accumulation -> fp32-grade matmuls.
// Phase 1: xw[b,t,g] = x@W_ih^T  (split bf16 MFMA GEMM, chunked into ws)
// Phase 2: sequential recurrence, 32 WGs = 8 batch-groups x 4 j-slices.
//   LN folded:  gates = rs*(Wtil h) - rs*mu*R + D + xw,  Wtil = W_hh*gamma.
//   Each WG parks its W-quarter hi+lo (256KB bf16) in VGPRs (asm-pinned).
//   Per-step inter-WG exchange: relaxed agent atomics + waitcnt-ordered flag
//   (no threadfence / no release-acquire cache maintenance).

#define Bb 128
#define Ss 1024
#define Ii 256
#define Hh 256
#define G4v 1024
#define EPSF 1e-5f

typedef __bf16 bf16;
typedef __attribute__((ext_vector_type(8))) __bf16 bf16x8;
typedef __attribute__((ext_vector_type(4))) __bf16 bf16x4;
typedef __attribute__((ext_vector_type(4))) float f32x4;

static __device__ __forceinline__ f32x4 mfma16(bf16x8 a, bf16x8 b, f32x4 c) {
  return __builtin_amdgcn_mfma_f32_16x16x32_bf16(a, b, c, 0, 0, 0);
}
static __device__ __forceinline__ float sigm(float x) { return 1.0f / (1.0f + __expf(-x)); }
static __device__ __forceinline__ float tanhf_(float x) {
  float e = __expf(-2.0f * fabsf(x));
  float t = (1.0f - e) / (1.0f + e);
  return x < 0.0f ? -t : t;
}

// ---------------- prep kernels ----------------
__global__ void k_conv_wih(const float* __restrict__ W, bf16* __restrict__ hi,
                           bf16* __restrict__ lo) {
  int i = (blockIdx.x * 256 + threadIdx.x) * 4;
  f32x4 v = *(const f32x4*)(W + i);
  bf16x4 h_, l_;
#pragma unroll
  for (int j = 0; j < 4; ++j) {
    bf16 hh = (bf16)v[j];
    h_[j] = hh;
    l_[j] = (bf16)(v[j] - (float)hh);
  }
  *(bf16x4*)(hi + i) = h_;
  *(bf16x4*)(lo + i) = l_;
}

// Wtil = W_hh * gamma, fragment-linear: Wf[(ntg*8+kt)*64 + lane][8] holds
// B-frag elem: Wtil[g = ntg*16 + (lane&15)][k = kt*32 + (lane>>4)*8 + j]
__global__ void k_prep_whh(const float* __restrict__ W, const float* __restrict__ gamma,
                           bf16* __restrict__ Whi, bf16* __restrict__ Wlo) {
  int tid = blockIdx.x * 256 + threadIdx.x;  // 0..32767
  int lane = tid & 63;
  int fk = tid >> 6;
  int ntg = fk >> 3, kt = fk & 7;
  int g = ntg * 16 + (lane & 15);
  int k = kt * 32 + ((lane >> 4) << 3);
  bf16x8 rh, rl;
#pragma unroll
  for (int j = 0; j < 8; ++j) {
    float wv = W[g * Hh + k + j] * gamma[k + j];
    bf16 hh = (bf16)wv;
    rh[j] = hh;
    rl[j] = (bf16)(wv - (float)hh);
  }
  *(bf16x8*)(Whi + (size_t)tid * 8) = rh;
  *(bf16x8*)(Wlo + (size_t)tid * 8) = rl;
}

__global__ void k_prep_rd(const float* __restrict__ W, const float* __restrict__ gamma,
                          const float* __restrict__ beta, const float* __restrict__ bih,
                          const float* __restrict__ bhh, float* __restrict__ RD) {
  int g = blockIdx.x * 256 + threadIdx.x;  // 1024 total
  float r = 0.f, d = 0.f;
  for (int k = 0; k < Hh; ++k) {
    float w = W[g * Hh + k];
    r += w * gamma[k];
    d += w * beta[k];
  }
  RD[2 * g] = r;
  RD[2 * g + 1] = d + bih[g] + bhh[g];
}

// ---------------- xw GEMM (split precision) ----------------
__global__ __launch_bounds__(256, 2) void k_gemm(const float* __restrict__ x,
                                                 const bf16* __restrict__ Whi,
                                                 const bf16* __restrict__ Wlo,
                                                 float* __restrict__ xw,
                                                 int t0, int Tc, int ntb) {
  __shared__ bf16 Bs[2][128 * 128];  // [plane][row*128+col], rows XOR-swizzled
  int bid = blockIdx.x;
  int b = bid & 127;
  int r2 = bid >> 7;
  int tb = r2 % ntb;
  int gt = r2 / ntb;
  int g0 = gt * 128;
  int tid = threadIdx.x, w = tid >> 6, lane = tid & 63;
  int li = lane & 15, lg = lane >> 4;
  char* BsB = (char*)Bs;
  int tbase = tb * 128 + 32 * w;
  f32x4 acc[2][8];
#pragma unroll
  for (int mt = 0; mt < 2; ++mt)
#pragma unroll
    for (int nt = 0; nt < 8; ++nt) acc[mt][nt] = (f32x4){0.f, 0.f, 0.f, 0.f};

  for (int kp = 0; kp < 2; ++kp) {
#pragma unroll
    for (int it = 0; it < 8; ++it) {
      int p = it * 4096 + tid * 16;  // bytes within 32KB plane
      int row = p >> 8, colb = p & 255;
      size_t goff = (size_t)(g0 + row) * 512 + kp * 256 + colb;
      int dst = row * 256 + (colb ^ ((row & 7) << 4));
      *(bf16x8*)(BsB + dst) = *(const bf16x8*)((const char*)Whi + goff);
      *(bf16x8*)(BsB + 32768 + dst) = *(const bf16x8*)((const char*)Wlo + goff);
    }
    __syncthreads();
#pragma unroll
    for (int kt = 0; kt < 4; ++kt) {
      int kl = kt * 32 + lg * 8;
      int kgl = kp * 128 + kl;
      bf16x8 ah[2], al[2];
#pragma unroll
      for (int mt = 0; mt < 2; ++mt) {
        int t = t0 + tbase + 16 * mt + li;
        const float* xp = x + ((size_t)b * Ss + t) * Ii + kgl;
        f32x4 f0 = *(const f32x4*)xp;
        f32x4 f1 = *(const f32x4*)(xp + 4);
        bf16x8 hv, lv;
#pragma unroll
        for (int j = 0; j < 4; ++j) {
          bf16 h0 = (bf16)f0[j];
          hv[j] = h0;
          lv[j] = (bf16)(f0[j] - (float)h0);
          bf16 h1 = (bf16)f1[j];
          hv[4 + j] = h1;
          lv[4 + j] = (bf16)(f1[j] - (float)h1);
        }
        ah[mt] = hv;
        al[mt] = lv;
      }
#pragma unroll
      for (int nt = 0; nt < 8; ++nt) {
        int grow = nt * 16 + li;
        int off = grow * 256 + ((kl * 2) ^ ((grow & 7) << 4));
        bf16x8 bh = *(const bf16x8*)(BsB + off);
        bf16x8 bl = *(const bf16x8*)(BsB + 32768 + off);
#pragma unroll
        for (int mt = 0; mt < 2; ++mt) {
          acc[mt][nt] = mfma16(ah[mt], bh, acc[mt][nt]);
          acc[mt][nt] = mfma16(ah[mt], bl, acc[mt][nt]);
          acc[mt][nt] = mfma16(al[mt], bh, acc[mt][nt]);
        }
      }
    }
    __syncthreads();
  }
#pragma unroll
  for (int mt = 0; mt < 2; ++mt)
#pragma unroll
    for (int nt = 0; nt < 8; ++nt)
#pragma unroll
      for (int r = 0; r < 4; ++r) {
        int tl = tbase + 16 * mt + lg * 4 + r;
        int g = g0 + nt * 16 + li;
        xw[((size_t)b * Tc + tl) * G4v + g] = acc[mt][nt][r];
      }
}

// ---------------- recurrence ----------------
// grid: 32 blocks, bid = q*8 + grp; block 256 thr / 4 waves.
__global__ __launch_bounds__(256, 1) void k_recur(
    const bf16* __restrict__ Whi_f, const bf16* __restrict__ Wlo_f,
    const float* __restrict__ xw, const int* __restrict__ mask,
    const float* __restrict__ RD, float* __restrict__ st_h, float* __restrict__ st_c,
    float* __restrict__ st_o, float* pub_h, float* pub_s, int* flags,
    float* __restrict__ out, int t0, int Tc, int first, int last) {
  __shared__ bf16 hb[2][16 * 256];   // h hi/lo planes, byte ^= (row&7)<<4 swizzle
  __shared__ float murs[16][2];      // (mu*rs, rs) per batch row
  __shared__ float spw[4][16][2];    // per-wave per-row partial stats
  __shared__ float sown[32];         // own-slice row stats (s,ss interleaved)
  __shared__ float spart[16][16][2]; // init-path only
  int bid = blockIdx.x;
  int grp = bid & 7, q = bid >> 3;
  int tid = threadIdx.x, w = tid >> 6, lane = tid & 63;
  int li = lane & 15, lg = lane >> 4;
  int b0 = grp * 16;
  int jloc = (q * 4 + w) * 16 + li;
  char* hbB = (char*)hb;

  // park this wave's W-quarter (hi+lo) in VGPRs; asm-pin against remat
  bf16x8 wph[4][8], wpl[4][8];
#pragma unroll
  for (int c = 0; c < 4; ++c)
#pragma unroll
    for (int kt = 0; kt < 8; ++kt) {
      int ntg = c * 16 + q * 4 + w;
      size_t off = ((size_t)(ntg * 8 + kt) * 64 + lane) * 8;
      wph[c][kt] = *(const bf16x8*)(Whi_f + off);
      wpl[c][kt] = *(const bf16x8*)(Wlo_f + off);
      asm volatile("" : "+v"(wph[c][kt]), "+v"(wpl[c][kt]));
    }
  float Rr[4], Dd[4];
#pragma unroll
  for (int c = 0; c < 4; ++c) {
    int g = c * 256 + jloc;
    Rr[c] = RD[2 * g];
    Dd[c] = RD[2 * g + 1];
  }

  float cst[4], ost[4];
  if (first) {
#pragma unroll
    for (int i = 0; i < 16; ++i) {
      hb[0][tid * 16 + i] = (bf16)0.0f;
      hb[1][tid * 16 + i] = (bf16)0.0f;
    }
#pragma unroll
    for (int r = 0; r < 4; ++r) { cst[r] = 0.f; ost[r] = 0.f; }
    if (tid < 16) { murs[tid][0] = 0.f; murs[tid][1] = rsqrtf(EPSF); }
  } else {
    int row = tid >> 4, jseg = (tid & 15) * 16;
    float s = 0.f, ss = 0.f;
#pragma unroll
    for (int i = 0; i < 16; ++i) {
      float v = st_h[(size_t)(b0 + row) * Hh + jseg + i];
      s += v;
      ss += v * v;
      bf16 hh = (bf16)v;
      int boff = row * 512 + (((jseg + i) * 2) ^ ((row & 7) << 4));
      *(bf16*)(hbB + boff) = hh;
      *(bf16*)(hbB + 8192 + boff) = (bf16)(v - (float)hh);
    }
    spart[row][tid & 15][0] = s;
    spart[row][tid & 15][1] = ss;
#pragma unroll
    for (int r = 0; r < 4; ++r) {
      int m = lg * 4 + r;
      cst[r] = st_c[(size_t)(b0 + m) * Hh + jloc];
      ost[r] = st_o[(size_t)(b0 + m) * Hh + jloc];
    }
    __syncthreads();
    if (tid < 16) {
      float s2 = 0.f, ss2 = 0.f;
#pragma unroll
      for (int i = 0; i < 16; ++i) { s2 += spart[tid][i][0]; ss2 += spart[tid][i][1]; }
      float mu = s2 * (1.f / 256.f);
      float var = ss2 * (1.f / 256.f) - mu * mu;
      float rs = rsqrtf(var + EPSF);
      murs[tid][0] = mu * rs;
      murs[tid][1] = rs;
    }
  }
  __syncthreads();

  // preload xw/mask for tl=0
  float xwv[4][4];
  int mk[4];
#pragma unroll
  for (int c = 0; c < 4; ++c)
#pragma unroll
    for (int r = 0; r < 4; ++r)
      xwv[c][r] = xw[((size_t)(b0 + lg * 4 + r) * Tc + 0) * G4v + c * 256 + jloc];
#pragma unroll
  for (int r = 0; r < 4; ++r) mk[r] = mask[(size_t)(b0 + lg * 4 + r) * Ss + t0];

  for (int tl = 0; tl < Tc; ++tl) {
    int tg = t0 + tl;
    int tln = (tl + 1 < Tc) ? tl + 1 : Tc - 1;
    float xwn[4][4];
    int mkn[4];
#pragma unroll
    for (int c = 0; c < 4; ++c)
#pragma unroll
      for (int r = 0; r < 4; ++r)
        xwn[c][r] = xw[((size_t)(b0 + lg * 4 + r) * Tc + tln) * G4v + c * 256 + jloc];
#pragma unroll
    for (int r = 0; r < 4; ++r) mkn[r] = mask[(size_t)(b0 + lg * 4 + r) * Ss + t0 + tln];

    // P1: split MFMA  gates_acc = Wtil * h
    f32x4 acc[4];
#pragma unroll
    for (int c = 0; c < 4; ++c) acc[c] = (f32x4){0.f, 0.f, 0.f, 0.f};
#pragma unroll
    for (int kt = 0; kt < 8; ++kt) {
      int kk = kt * 32 + lg * 8;
      int aoff = li * 512 + ((kk * 2) ^ ((li & 7) << 4));
      bf16x8 ah = *(const bf16x8*)(hbB + aoff);
      bf16x8 al = *(const bf16x8*)(hbB + 8192 + aoff);
#pragma unroll
      for (int c = 0; c < 4; ++c) {
        acc[c] = mfma16(ah, wph[c][kt], acc[c]);
        acc[c] = mfma16(ah, wpl[c][kt], acc[c]);
        acc[c] = mfma16(al, wph[c][kt], acc[c]);
      }
    }
    float mrs[4], rsv[4];
#pragma unroll
    for (int r = 0; r < 4; ++r) {
      int m = lg * 4 + r;
      mrs[r] = murs[m][0];
      rsv[r] = murs[m][1];
    }
    __syncthreads();  // SYNC_A: all waves done reading hb/murs of step t

    // P2: gates -> c,h,out; publish h (relaxed agent atomics) + own hb slice
    int slot = (tg + 1) & 1;
    float* ph = pub_h + (size_t)(slot * 32 + bid) * 1024;
    float hnew[4];
#pragma unroll
    for (int r = 0; r < 4; ++r) {
      float i_ = acc[0][r] * rsv[r] - mrs[r] * Rr[0] + Dd[0] + xwv[0][r];
      float f_ = acc[1][r] * rsv[r] - mrs[r] * Rr[1] + Dd[1] + xwv[1][r];
      float g_ = acc[2][r] * rsv[r] - mrs[r] * Rr[2] + Dd[2] + xwv[2][r];
      float o_ = acc[3][r] * rsv[r] - mrs[r] * Rr[3] + Dd[3] + xwv[3][r];
      float cn = sigm(f_) * cst[r] + sigm(i_) * tanhf_(g_);
      float hn = sigm(o_) * tanhf_(cn);
      cst[r] = cn;
      ost[r] = mk[r] ? ost[r] : hn;
      hnew[r] = hn;
    }
#pragma unroll
    for (int r = 0; r < 4; ++r) {
      int m = lg * 4 + r;
      float hn = hnew[r];
      bf16 hh = (bf16)hn;
      int boff = m * 512 + ((jloc * 2) ^ ((m & 7) << 4));
      *(bf16*)(hbB + boff) = hh;
      *(bf16*)(hbB + 8192 + boff) = (bf16)(hn - (float)hh);
      __hip_atomic_store(&ph[m * 64 + (w * 16 + li)], hn, __ATOMIC_RELAXED,
                         __HIP_MEMORY_SCOPE_AGENT);
    }
    if (last && tl == Tc - 1) {
#pragma unroll
      for (int r = 0; r < 4; ++r) out[(size_t)(b0 + lg * 4 + r) * Hh + jloc] = ost[r];
    }
    if (tl == Tc - 1) {
#pragma unroll
      for (int r = 0; r < 4; ++r) {
        int m = lg * 4 + r;
        st_h[(size_t)(b0 + m) * Hh + jloc] = hnew[r];
        st_c[(size_t)(b0 + m) * Hh + jloc] = cst[r];
        st_o[(size_t)(b0 + m) * Hh + jloc] = ost[r];
      }
    }
    // own-slice LN partial stats: shfl_xor reduce over the 16 li lanes
    {
      float sr[4], qr[4];
#pragma unroll
      for (int r = 0; r < 4; ++r) { sr[r] = hnew[r]; qr[r] = hnew[r] * hnew[r]; }
#pragma unroll
      for (int msk = 1; msk < 16; msk <<= 1)
#pragma unroll
        for (int r = 0; r < 4; ++r) {
          sr[r] += __shfl_xor(sr[r], msk);
          qr[r] += __shfl_xor(qr[r], msk);
        }
      if (li == 0)
#pragma unroll
        for (int r = 0; r < 4; ++r) {
          spw[w][lg * 4 + r][0] = sr[r];
          spw[w][lg * 4 + r][1] = qr[r];
        }
    }
    // rotate prefetch
#pragma unroll
    for (int c = 0; c < 4; ++c)
#pragma unroll
      for (int r = 0; r < 4; ++r) xwv[c][r] = xwn[c][r];
#pragma unroll
    for (int r = 0; r < 4; ++r) mk[r] = mkn[r];

    __syncthreads();  // SYNC_B2: spw ready
    if (tid < 32) {
      int row = tid >> 1, comp = tid & 1;
      float v = spw[0][row][comp] + spw[1][row][comp] + spw[2][row][comp] +
                spw[3][row][comp];
      sown[tid] = v;
      __hip_atomic_store(&pub_s[(size_t)(slot * 32 + bid) * 32 + tid], v,
                         __ATOMIC_RELAXED, __HIP_MEMORY_SCOPE_AGENT);
    }
    asm volatile("s_waitcnt vmcnt(0)" ::: "memory");
    __syncthreads();  // SYNC_B: all pub stores globally visible
    if (tid == 0)
      __hip_atomic_store(&flags[bid], tg + 1, __ATOMIC_RELAXED, __HIP_MEMORY_SCOPE_AGENT);
    if (tid >= 1 && tid <= 3) {
      int qq = (q + tid) & 3;
      int pbid = qq * 8 + grp;
      int cnt = 0;
      while (__hip_atomic_load(&flags[pbid], __ATOMIC_RELAXED, __HIP_MEMORY_SCOPE_AGENT) <
             tg + 1) {
        if (++cnt > (1 << 24)) break;  // hang insurance
      }
    }
    __syncthreads();  // SYNC_C: partner data ready

    // P3: gather 3 partner fp32 slices (relaxed atomic loads), split into planes
#pragma unroll
    for (int pi = 1; pi < 4; ++pi) {
      int qq = (q + pi) & 3;
      int pbid = qq * 8 + grp;
      float* src = pub_h + (size_t)(slot * 32 + pbid) * 1024;
      int idx = tid * 4;
      int row = idx >> 6, jj = idx & 63;
      float v[4];
#pragma unroll
      for (int e = 0; e < 4; ++e)
        v[e] = __hip_atomic_load(&src[idx + e], __ATOMIC_RELAXED, __HIP_MEMORY_SCOPE_AGENT);
      bf16x4 h4, l4;
#pragma unroll
      for (int e = 0; e < 4; ++e) {
        bf16 hh = (bf16)v[e];
        h4[e] = hh;
        l4[e] = (bf16)(v[e] - (float)hh);
      }
      int boff = row * 512 + (((qq * 64 + jj) * 2) ^ ((row & 7) << 4));
      *(bf16x4*)(hbB + boff) = h4;
      *(bf16x4*)(hbB + 8192 + boff) = l4;
    }
    // LN scalars for next step from own + 3 partner partials
    if (tid < 16) {
      int row = tid;
      float s = sown[2 * row], ss = sown[2 * row + 1];
#pragma unroll
      for (int pi = 1; pi < 4; ++pi) {
        int qq = (q + pi) & 3;
        int pbid = qq * 8 + grp;
        float* psb = pub_s + (size_t)(slot * 32 + pbid) * 32;
        s += __hip_atomic_load(&psb[2 * row], __ATOMIC_RELAXED, __HIP_MEMORY_SCOPE_AGENT);
        ss += __hip_atomic_load(&psb[2 * row + 1], __ATOMIC_RELAXED, __HIP_MEMORY_SCOPE_AGENT);
      }
      float mu = s * (1.f / 256.f);
      float var = ss * (1.f / 256.f) - mu * mu;
      float rs = rsqrtf(var + EPSF);
      murs[row][0] = mu * rs;
      murs[row][1] = rs;
    }
    __syncthreads();  // SYNC_D: hb + murs ready for next P1
  }
}

// ---------------- host ----------------
extern "C" void kernel_launch(void* const* d_in, const int* in_sizes, int n_in,
                              void* d_out, int out_size, void* d_ws, size_t ws_size,
                              hipStream_t stream) {
  (void)in_sizes; (void)n_in; (void)out_size;
  const float* x = (const float*)d_in[0];
  const int* mask = (const int*)d_in[1];
  const float* Wih = (const float*)d_in[2];
  const float* Whh = (const float*)d_in[3];
  const float* bih = (const float*)d_in[4];
  const float* bhh = (const float*)d_in[5];
  const float* gamma = (const float*)d_in[6];
  const float* beta = (const float*)d_in[7];
  float* outp = (float*)d_out;
  char* ws = (char*)d_ws;

  const size_t extra = 4 * (512u << 10) + (8u << 10) + 3 * (128u << 10) +
                       (256u << 10) + (16u << 10) + (64u << 10);
  int Tc = 128;
  if (ws_size >= (size_t)1024 * 524288 + extra) Tc = 1024;
  else if (ws_size >= (size_t)512 * 524288 + extra) Tc = 512;
  else if (ws_size >= (size_t)256 * 524288 + extra) Tc = 256;

  size_t o = 0;
  auto take = [&](size_t bytes) { size_t r = o; o += (bytes + 255) & ~(size_t)255; return r; };
  size_t xw_off = take((size_t)Bb * Tc * G4v * 4);
  size_t wihh_off = take(512u << 10);
  size_t wihl_off = take(512u << 10);
  size_t whhh_off = take(512u << 10);
  size_t whhl_off = take(512u << 10);
  size_t rd_off = take(8u << 10);
  size_t sth_off = take(128u << 10);
  size_t stc_off = take(128u << 10);
  size_t sto_off = take(128u << 10);
  size_t pub_off = take(256u << 10);
  size_t pubs_off = take(8u << 10);
  size_t flg_off = take(256);

  bf16* wihh = (bf16*)(ws + wihh_off);
  bf16* wihl = (bf16*)(ws + wihl_off);
  bf16* whhh = (bf16*)(ws + whhh_off);
  bf16* whhl = (bf16*)(ws + whhl_off);
  float* rd = (float*)(ws + rd_off);
  float* xwp = (float*)(ws + xw_off);
  float* sth = (float*)(ws + sth_off);
  float* stc = (float*)(ws + stc_off);
  float* sto = (float*)(ws + sto_off);
  float* pubh = (float*)(ws + pub_off);
  float* pubs = (float*)(ws + pubs_off);
  int* flg = (int*)(ws + flg_off);

  hipMemsetAsync(flg, 0, 256, stream);
  k_conv_wih<<<dim3(256), dim3(256), 0, stream>>>(Wih, wihh, wihl);
  k_prep_whh<<<dim3(128), dim3(256), 0, stream>>>(Whh, gamma, whhh, whhl);
  k_prep_rd<<<dim3(4), dim3(256), 0, stream>>>(Whh, gamma, beta, bih, bhh, rd);

  int nchunk = Ss / Tc;
  int ntb = Tc / 128;
  for (int ci = 0; ci < nchunk; ++ci) {
    int t0 = ci * Tc;
    k_gemm<<<dim3(8 * ntb * 128), dim3(256), 0, stream>>>(x, wihh, wihl, xwp, t0, Tc, ntb);
    k_recur<<<dim3(32), dim3(256), 0, stream>>>(whhh, whhl, xwp, mask, rd, sth, stc, sto,
                                                pubh, pubs, flg, outp, t0, Tc,
                                                ci == 0 ? 1 : 0, ci == nchunk - 1 ? 1 : 0);
  }
}

// Round 4
// 4847.383 us; speedup vs baseline: 1.4571x; 1.0851x over previous
//
#include <hip/hip_runtime.h>
#include <hip/hip_bf16.h>
#include <stdint.h>

// ContainedLSTM: B=128, S=1024, I=256, H=256.
// Split-precision (Ootomo 2-term bf16): v = v_hi + v_lo, product
// hi*hi + hi*lo + lo*hi with fp32 MFMA accumulation -> fp32-grade matmuls.
// Phase 1: xw[b,t,g] = x@W_ih^T  (split bf16 MFMA GEMM, chunked into ws)
// Phase 2: sequential recurrence, 32 WGs = 8 batch-groups x 4 j-slices.
//   LN folded:  gates = rs*(Wtil h) - rs*mu*R + D + xw,  Wtil = W_hh*gamma.
//   Each WG parks its W-quarter hi+lo (256 regs/lane) in AGPRS ("+a" pin) --
//   the VGPR file caps at 256 addressable regs, so "+v" parking spilled to
//   scratch (R3: 216 VGPR, 256KB/block/step scratch re-read = the bottleneck).
//   Per-step inter-WG exchange: relaxed agent atomics + waitcnt-ordered flag.

#define Bb 128
#define Ss 1024
#define Ii 256
#define Hh 256
#define G4v 1024
#define EPSF 1e-5f

typedef __bf16 bf16;
typedef __attribute__((ext_vector_type(8))) __bf16 bf16x8;
typedef __attribute__((ext_vector_type(4))) __bf16 bf16x4;
typedef __attribute__((ext_vector_type(4))) float f32x4;

static __device__ __forceinline__ f32x4 mfma16(bf16x8 a, bf16x8 b, f32x4 c) {
  return __builtin_amdgcn_mfma_f32_16x16x32_bf16(a, b, c, 0, 0, 0);
}
static __device__ __forceinline__ float sigm(float x) { return 1.0f / (1.0f + __expf(-x)); }
static __device__ __forceinline__ float tanhf_(float x) {
  float e = __expf(-2.0f * fabsf(x));
  float t = (1.0f - e) / (1.0f + e);
  return x < 0.0f ? -t : t;
}

// ---------------- prep kernels ----------------
__global__ void k_conv_wih(const float* __restrict__ W, bf16* __restrict__ hi,
                           bf16* __restrict__ lo) {
  int i = (blockIdx.x * 256 + threadIdx.x) * 4;
  f32x4 v = *(const f32x4*)(W + i);
  bf16x4 h_, l_;
#pragma unroll
  for (int j = 0; j < 4; ++j) {
    bf16 hh = (bf16)v[j];
    h_[j] = hh;
    l_[j] = (bf16)(v[j] - (float)hh);
  }
  *(bf16x4*)(hi + i) = h_;
  *(bf16x4*)(lo + i) = l_;
}

// Wtil = W_hh * gamma, fragment-linear: Wf[(ntg*8+kt)*64 + lane][8] holds
// B-frag elem: Wtil[g = ntg*16 + (lane&15)][k = kt*32 + (lane>>4)*8 + j]
__global__ void k_prep_whh(const float* __restrict__ W, const float* __restrict__ gamma,
                           bf16* __restrict__ Whi, bf16* __restrict__ Wlo) {
  int tid = blockIdx.x * 256 + threadIdx.x;  // 0..32767
  int lane = tid & 63;
  int fk = tid >> 6;
  int ntg = fk >> 3, kt = fk & 7;
  int g = ntg * 16 + (lane & 15);
  int k = kt * 32 + ((lane >> 4) << 3);
  bf16x8 rh, rl;
#pragma unroll
  for (int j = 0; j < 8; ++j) {
    float wv = W[g * Hh + k + j] * gamma[k + j];
    bf16 hh = (bf16)wv;
    rh[j] = hh;
    rl[j] = (bf16)(wv - (float)hh);
  }
  *(bf16x8*)(Whi + (size_t)tid * 8) = rh;
  *(bf16x8*)(Wlo + (size_t)tid * 8) = rl;
}

__global__ void k_prep_rd(const float* __restrict__ W, const float* __restrict__ gamma,
                          const float* __restrict__ beta, const float* __restrict__ bih,
                          const float* __restrict__ bhh, float* __restrict__ RD) {
  int g = blockIdx.x * 256 + threadIdx.x;  // 1024 total
  float r = 0.f, d = 0.f;
  for (int k = 0; k < Hh; ++k) {
    float w = W[g * Hh + k];
    r += w * gamma[k];
    d += w * beta[k];
  }
  RD[2 * g] = r;
  RD[2 * g + 1] = d + bih[g] + bhh[g];
}

// ---------------- xw GEMM (split precision) ----------------
__global__ __launch_bounds__(256, 2) void k_gemm(const float* __restrict__ x,
                                                 const bf16* __restrict__ Whi,
                                                 const bf16* __restrict__ Wlo,
                                                 float* __restrict__ xw,
                                                 int t0, int Tc, int ntb) {
  __shared__ bf16 Bs[2][128 * 128];  // [plane][row*128+col], rows XOR-swizzled
  int bid = blockIdx.x;
  int b = bid & 127;
  int r2 = bid >> 7;
  int tb = r2 % ntb;
  int gt = r2 / ntb;
  int g0 = gt * 128;
  int tid = threadIdx.x, w = tid >> 6, lane = tid & 63;
  int li = lane & 15, lg = lane >> 4;
  char* BsB = (char*)Bs;
  int tbase = tb * 128 + 32 * w;
  f32x4 acc[2][8];
#pragma unroll
  for (int mt = 0; mt < 2; ++mt)
#pragma unroll
    for (int nt = 0; nt < 8; ++nt) acc[mt][nt] = (f32x4){0.f, 0.f, 0.f, 0.f};

  for (int kp = 0; kp < 2; ++kp) {
#pragma unroll
    for (int it = 0; it < 8; ++it) {
      int p = it * 4096 + tid * 16;  // bytes within 32KB plane
      int row = p >> 8, colb = p & 255;
      size_t goff = (size_t)(g0 + row) * 512 + kp * 256 + colb;
      int dst = row * 256 + (colb ^ ((row & 7) << 4));
      *(bf16x8*)(BsB + dst) = *(const bf16x8*)((const char*)Whi + goff);
      *(bf16x8*)(BsB + 32768 + dst) = *(const bf16x8*)((const char*)Wlo + goff);
    }
    __syncthreads();
#pragma unroll
    for (int kt = 0; kt < 4; ++kt) {
      int kl = kt * 32 + lg * 8;
      int kgl = kp * 128 + kl;
      bf16x8 ah[2], al[2];
#pragma unroll
      for (int mt = 0; mt < 2; ++mt) {
        int t = t0 + tbase + 16 * mt + li;
        const float* xp = x + ((size_t)b * Ss + t) * Ii + kgl;
        f32x4 f0 = *(const f32x4*)xp;
        f32x4 f1 = *(const f32x4*)(xp + 4);
        bf16x8 hv, lv;
#pragma unroll
        for (int j = 0; j < 4; ++j) {
          bf16 h0 = (bf16)f0[j];
          hv[j] = h0;
          lv[j] = (bf16)(f0[j] - (float)h0);
          bf16 h1 = (bf16)f1[j];
          hv[4 + j] = h1;
          lv[4 + j] = (bf16)(f1[j] - (float)h1);
        }
        ah[mt] = hv;
        al[mt] = lv;
      }
#pragma unroll
      for (int nt = 0; nt < 8; ++nt) {
        int grow = nt * 16 + li;
        int off = grow * 256 + ((kl * 2) ^ ((grow & 7) << 4));
        bf16x8 bh = *(const bf16x8*)(BsB + off);
        bf16x8 bl = *(const bf16x8*)(BsB + 32768 + off);
#pragma unroll
        for (int mt = 0; mt < 2; ++mt) {
          acc[mt][nt] = mfma16(ah[mt], bh, acc[mt][nt]);
          acc[mt][nt] = mfma16(ah[mt], bl, acc[mt][nt]);
          acc[mt][nt] = mfma16(al[mt], bh, acc[mt][nt]);
        }
      }
    }
    __syncthreads();
  }
#pragma unroll
  for (int mt = 0; mt < 2; ++mt)
#pragma unroll
    for (int nt = 0; nt < 8; ++nt)
#pragma unroll
      for (int r = 0; r < 4; ++r) {
        int tl = tbase + 16 * mt + lg * 4 + r;
        int g = g0 + nt * 16 + li;
        xw[((size_t)b * Tc + tl) * G4v + g] = acc[mt][nt][r];
      }
}

// ---------------- recurrence ----------------
// grid: 32 blocks, bid = q*8 + grp; block 256 thr / 4 waves.
__global__ __launch_bounds__(256, 1) void k_recur(
    const bf16* __restrict__ Whi_f, const bf16* __restrict__ Wlo_f,
    const float* __restrict__ xw, const int* __restrict__ mask,
    const float* __restrict__ RD, float* __restrict__ st_h, float* __restrict__ st_c,
    float* __restrict__ st_o, float* pub_h, float* pub_s, int* flags,
    float* __restrict__ out, int t0, int Tc, int first, int last) {
  __shared__ bf16 hb[2][16 * 256];   // h hi/lo planes, byte ^= (row&7)<<4 swizzle
  __shared__ float murs[16][2];      // (mu*rs, rs) per batch row
  __shared__ float spw[4][16][2];    // per-wave per-row partial stats
  __shared__ float sown[32];         // own-slice row stats (s,ss interleaved)
  __shared__ float spart[16][16][2]; // init-path only
  int bid = blockIdx.x;
  int grp = bid & 7, q = bid >> 3;
  int tid = threadIdx.x, w = tid >> 6, lane = tid & 63;
  int li = lane & 15, lg = lane >> 4;
  int b0 = grp * 16;
  int jloc = (q * 4 + w) * 16 + li;
  char* hbB = (char*)hb;

  // park this wave's W-quarter (hi+lo) in AGPRs (outside the 256-VGPR cap);
  // MFMA reads A/B from AGPR directly on gfx950.
  bf16x8 wph[4][8], wpl[4][8];
#pragma unroll
  for (int c = 0; c < 4; ++c)
#pragma unroll
    for (int kt = 0; kt < 8; ++kt) {
      int ntg = c * 16 + q * 4 + w;
      size_t off = ((size_t)(ntg * 8 + kt) * 64 + lane) * 8;
      wph[c][kt] = *(const bf16x8*)(Whi_f + off);
      wpl[c][kt] = *(const bf16x8*)(Wlo_f + off);
      asm volatile("" : "+a"(wph[c][kt]), "+a"(wpl[c][kt]));
    }
  float Rr[4], Dd[4];
#pragma unroll
  for (int c = 0; c < 4; ++c) {
    int g = c * 256 + jloc;
    Rr[c] = RD[2 * g];
    Dd[c] = RD[2 * g + 1];
  }

  float cst[4], ost[4];
  if (first) {
#pragma unroll
    for (int i = 0; i < 16; ++i) {
      hb[0][tid * 16 + i] = (bf16)0.0f;
      hb[1][tid * 16 + i] = (bf16)0.0f;
    }
#pragma unroll
    for (int r = 0; r < 4; ++r) { cst[r] = 0.f; ost[r] = 0.f; }
    if (tid < 16) { murs[tid][0] = 0.f; murs[tid][1] = rsqrtf(EPSF); }
  } else {
    int row = tid >> 4, jseg = (tid & 15) * 16;
    float s = 0.f, ss = 0.f;
#pragma unroll
    for (int i = 0; i < 16; ++i) {
      float v = st_h[(size_t)(b0 + row) * Hh + jseg + i];
      s += v;
      ss += v * v;
      bf16 hh = (bf16)v;
      int boff = row * 512 + (((jseg + i) * 2) ^ ((row & 7) << 4));
      *(bf16*)(hbB + boff) = hh;
      *(bf16*)(hbB + 8192 + boff) = (bf16)(v - (float)hh);
    }
    spart[row][tid & 15][0] = s;
    spart[row][tid & 15][1] = ss;
#pragma unroll
    for (int r = 0; r < 4; ++r) {
      int m = lg * 4 + r;
      cst[r] = st_c[(size_t)(b0 + m) * Hh + jloc];
      ost[r] = st_o[(size_t)(b0 + m) * Hh + jloc];
    }
    __syncthreads();
    if (tid < 16) {
      float s2 = 0.f, ss2 = 0.f;
#pragma unroll
      for (int i = 0; i < 16; ++i) { s2 += spart[tid][i][0]; ss2 += spart[tid][i][1]; }
      float mu = s2 * (1.f / 256.f);
      float var = ss2 * (1.f / 256.f) - mu * mu;
      float rs = rsqrtf(var + EPSF);
      murs[tid][0] = mu * rs;
      murs[tid][1] = rs;
    }
  }
  __syncthreads();

  // preload xw/mask for tl=0
  float xwv[4][4];
  int mk[4];
#pragma unroll
  for (int c = 0; c < 4; ++c)
#pragma unroll
    for (int r = 0; r < 4; ++r)
      xwv[c][r] = xw[((size_t)(b0 + lg * 4 + r) * Tc + 0) * G4v + c * 256 + jloc];
#pragma unroll
  for (int r = 0; r < 4; ++r) mk[r] = mask[(size_t)(b0 + lg * 4 + r) * Ss + t0];

  for (int tl = 0; tl < Tc; ++tl) {
    int tg = t0 + tl;
    int tln = (tl + 1 < Tc) ? tl + 1 : Tc - 1;
    float xwn[4][4];
    int mkn[4];
#pragma unroll
    for (int c = 0; c < 4; ++c)
#pragma unroll
      for (int r = 0; r < 4; ++r)
        xwn[c][r] = xw[((size_t)(b0 + lg * 4 + r) * Tc + tln) * G4v + c * 256 + jloc];
#pragma unroll
    for (int r = 0; r < 4; ++r) mkn[r] = mask[(size_t)(b0 + lg * 4 + r) * Ss + t0 + tln];

    // P1: split MFMA  gates_acc = Wtil * h
    f32x4 acc[4];
#pragma unroll
    for (int c = 0; c < 4; ++c) acc[c] = (f32x4){0.f, 0.f, 0.f, 0.f};
#pragma unroll
    for (int kt = 0; kt < 8; ++kt) {
      int kk = kt * 32 + lg * 8;
      int aoff = li * 512 + ((kk * 2) ^ ((li & 7) << 4));
      bf16x8 ah = *(const bf16x8*)(hbB + aoff);
      bf16x8 al = *(const bf16x8*)(hbB + 8192 + aoff);
#pragma unroll
      for (int c = 0; c < 4; ++c) {
        acc[c] = mfma16(ah, wph[c][kt], acc[c]);
        acc[c] = mfma16(ah, wpl[c][kt], acc[c]);
        acc[c] = mfma16(al, wph[c][kt], acc[c]);
      }
    }
    float mrs[4], rsv[4];
#pragma unroll
    for (int r = 0; r < 4; ++r) {
      int m = lg * 4 + r;
      mrs[r] = murs[m][0];
      rsv[r] = murs[m][1];
    }
    __syncthreads();  // SYNC_A: all waves done reading hb/murs of step t

    // P2: gates -> c,h,out; publish h (relaxed agent atomics) + own hb slice
    int slot = (tg + 1) & 1;
    float* ph = pub_h + (size_t)(slot * 32 + bid) * 1024;
    float hnew[4];
#pragma unroll
    for (int r = 0; r < 4; ++r) {
      float i_ = acc[0][r] * rsv[r] - mrs[r] * Rr[0] + Dd[0] + xwv[0][r];
      float f_ = acc[1][r] * rsv[r] - mrs[r] * Rr[1] + Dd[1] + xwv[1][r];
      float g_ = acc[2][r] * rsv[r] - mrs[r] * Rr[2] + Dd[2] + xwv[2][r];
      float o_ = acc[3][r] * rsv[r] - mrs[r] * Rr[3] + Dd[3] + xwv[3][r];
      float cn = sigm(f_) * cst[r] + sigm(i_) * tanhf_(g_);
      float hn = sigm(o_) * tanhf_(cn);
      cst[r] = cn;
      ost[r] = mk[r] ? ost[r] : hn;
      hnew[r] = hn;
    }
#pragma unroll
    for (int r = 0; r < 4; ++r) {
      int m = lg * 4 + r;
      float hn = hnew[r];
      bf16 hh = (bf16)hn;
      int boff = m * 512 + ((jloc * 2) ^ ((m & 7) << 4));
      *(bf16*)(hbB + boff) = hh;
      *(bf16*)(hbB + 8192 + boff) = (bf16)(hn - (float)hh);
      __hip_atomic_store(&ph[m * 64 + (w * 16 + li)], hn, __ATOMIC_RELAXED,
                         __HIP_MEMORY_SCOPE_AGENT);
    }
    if (last && tl == Tc - 1) {
#pragma unroll
      for (int r = 0; r < 4; ++r) out[(size_t)(b0 + lg * 4 + r) * Hh + jloc] = ost[r];
    }
    if (tl == Tc - 1) {
#pragma unroll
      for (int r = 0; r < 4; ++r) {
        int m = lg * 4 + r;
        st_h[(size_t)(b0 + m) * Hh + jloc] = hnew[r];
        st_c[(size_t)(b0 + m) * Hh + jloc] = cst[r];
        st_o[(size_t)(b0 + m) * Hh + jloc] = ost[r];
      }
    }
    // own-slice LN partial stats: shfl_xor reduce over the 16 li lanes
    {
      float sr[4], qr[4];
#pragma unroll
      for (int r = 0; r < 4; ++r) { sr[r] = hnew[r]; qr[r] = hnew[r] * hnew[r]; }
#pragma unroll
      for (int msk = 1; msk < 16; msk <<= 1)
#pragma unroll
        for (int r = 0; r < 4; ++r) {
          sr[r] += __shfl_xor(sr[r], msk);
          qr[r] += __shfl_xor(qr[r], msk);
        }
      if (li == 0)
#pragma unroll
        for (int r = 0; r < 4; ++r) {
          spw[w][lg * 4 + r][0] = sr[r];
          spw[w][lg * 4 + r][1] = qr[r];
        }
    }
    // rotate prefetch
#pragma unroll
    for (int c = 0; c < 4; ++c)
#pragma unroll
      for (int r = 0; r < 4; ++r) xwv[c][r] = xwn[c][r];
#pragma unroll
    for (int r = 0; r < 4; ++r) mk[r] = mkn[r];

    __syncthreads();  // SYNC_B2: spw ready
    if (tid < 32) {
      int row = tid >> 1, comp = tid & 1;
      float v = spw[0][row][comp] + spw[1][row][comp] + spw[2][row][comp] +
                spw[3][row][comp];
      sown[tid] = v;
      __hip_atomic_store(&pub_s[(size_t)(slot * 32 + bid) * 32 + tid], v,
                         __ATOMIC_RELAXED, __HIP_MEMORY_SCOPE_AGENT);
    }
    asm volatile("s_waitcnt vmcnt(0)" ::: "memory");
    __syncthreads();  // SYNC_B: all pub stores globally visible
    if (tid == 0)
      __hip_atomic_store(&flags[bid], tg + 1, __ATOMIC_RELAXED, __HIP_MEMORY_SCOPE_AGENT);
    if (tid >= 1 && tid <= 3) {
      int qq = (q + tid) & 3;
      int pbid = qq * 8 + grp;
      int cnt = 0;
      while (__hip_atomic_load(&flags[pbid], __ATOMIC_RELAXED, __HIP_MEMORY_SCOPE_AGENT) <
             tg + 1) {
        if (++cnt > (1 << 24)) break;  // hang insurance
      }
    }
    __syncthreads();  // SYNC_C: partner data ready

    // P3: gather 3 partner fp32 slices (relaxed atomic loads), split into planes
#pragma unroll
    for (int pi = 1; pi < 4; ++pi) {
      int qq = (q + pi) & 3;
      int pbid = qq * 8 + grp;
      float* src = pub_h + (size_t)(slot * 32 + pbid) * 1024;
      int idx = tid * 4;
      int row = idx >> 6, jj = idx & 63;
      float v[4];
#pragma unroll
      for (int e = 0; e < 4; ++e)
        v[e] = __hip_atomic_load(&src[idx + e], __ATOMIC_RELAXED, __HIP_MEMORY_SCOPE_AGENT);
      bf16x4 h4, l4;
#pragma unroll
      for (int e = 0; e < 4; ++e) {
        bf16 hh = (bf16)v[e];
        h4[e] = hh;
        l4[e] = (bf16)(v[e] - (float)hh);
      }
      int boff = row * 512 + (((qq * 64 + jj) * 2) ^ ((row & 7) << 4));
      *(bf16x4*)(hbB + boff) = h4;
      *(bf16x4*)(hbB + 8192 + boff) = l4;
    }
    // LN scalars for next step from own + 3 partner partials
    if (tid < 16) {
      int row = tid;
      float s = sown[2 * row], ss = sown[2 * row + 1];
#pragma unroll
      for (int pi = 1; pi < 4; ++pi) {
        int qq = (q + pi) & 3;
        int pbid = qq * 8 + grp;
        float* psb = pub_s + (size_t)(slot * 32 + pbid) * 32;
        s += __hip_atomic_load(&psb[2 * row], __ATOMIC_RELAXED, __HIP_MEMORY_SCOPE_AGENT);
        ss += __hip_atomic_load(&psb[2 * row + 1], __ATOMIC_RELAXED, __HIP_MEMORY_SCOPE_AGENT);
      }
      float mu = s * (1.f / 256.f);
      float var = ss * (1.f / 256.f) - mu * mu;
      float rs = rsqrtf(var + EPSF);
      murs[row][0] = mu * rs;
      murs[row][1] = rs;
    }
    __syncthreads();  // SYNC_D: hb + murs ready for next P1
  }
}

// ---------------- host ----------------
extern "C" void kernel_launch(void* const* d_in, const int* in_sizes, int n_in,
                              void* d_out, int out_size, void* d_ws, size_t ws_size,
                              hipStream_t stream) {
  (void)in_sizes; (void)n_in; (void)out_size;
  const float* x = (const float*)d_in[0];
  const int* mask = (const int*)d_in[1];
  const float* Wih = (const float*)d_in[2];
  const float* Whh = (const float*)d_in[3];
  const float* bih = (const float*)d_in[4];
  const float* bhh = (const float*)d_in[5];
  const float* gamma = (const float*)d_in[6];
  const float* beta = (const float*)d_in[7];
  float* outp = (float*)d_out;
  char* ws = (char*)d_ws;

  const size_t extra = 4 * (512u << 10) + (8u << 10) + 3 * (128u << 10) +
                       (256u << 10) + (16u << 10) + (64u << 10);
  int Tc = 128;
  if (ws_size >= (size_t)1024 * 524288 + extra) Tc = 1024;
  else if (ws_size >= (size_t)512 * 524288 + extra) Tc = 512;
  else if (ws_size >= (size_t)256 * 524288 + extra) Tc = 256;

  size_t o = 0;
  auto take = [&](size_t bytes) { size_t r = o; o += (bytes + 255) & ~(size_t)255; return r; };
  size_t xw_off = take((size_t)Bb * Tc * G4v * 4);
  size_t wihh_off = take(512u << 10);
  size_t wihl_off = take(512u << 10);
  size_t whhh_off = take(512u << 10);
  size_t whhl_off = take(512u << 10);
  size_t rd_off = take(8u << 10);
  size_t sth_off = take(128u << 10);
  size_t stc_off = take(128u << 10);
  size_t sto_off = take(128u << 10);
  size_t pub_off = take(256u << 10);
  size_t pubs_off = take(8u << 10);
  size_t flg_off = take(256);

  bf16* wihh = (bf16*)(ws + wihh_off);
  bf16* wihl = (bf16*)(ws + wihl_off);
  bf16* whhh = (bf16*)(ws + whhh_off);
  bf16* whhl = (bf16*)(ws + whhl_off);
  float* rd = (float*)(ws + rd_off);
  float* xwp = (float*)(ws + xw_off);
  float* sth = (float*)(ws + sth_off);
  float* stc = (float*)(ws + stc_off);
  float* sto = (float*)(ws + sto_off);
  float* pubh = (float*)(ws + pub_off);
  float* pubs = (float*)(ws + pubs_off);
  int* flg = (int*)(ws + flg_off);

  hipMemsetAsync(flg, 0, 256, stream);
  k_conv_wih<<<dim3(256), dim3(256), 0, stream>>>(Wih, wihh, wihl);
  k_prep_whh<<<dim3(128), dim3(256), 0, stream>>>(Whh, gamma, whhh, whhl);
  k_prep_rd<<<dim3(4), dim3(256), 0, stream>>>(Whh, gamma, beta, bih, bhh, rd);

  int nchunk = Ss / Tc;
  int ntb = Tc / 128;
  for (int ci = 0; ci < nchunk; ++ci) {
    int t0 = ci * Tc;
    k_gemm<<<dim3(8 * ntb * 128), dim3(256), 0, stream>>>(x, wihh, wihl, xwp, t0, Tc, ntb);
    k_recur<<<dim3(32), dim3(256), 0, stream>>>(whhh, whhl, xwp, mask, rd, sth, stc, sto,
                                                pubh, pubs, flg, outp, t0, Tc,
                                                ci == 0 ? 1 : 0, ci == nchunk - 1 ? 1 : 0);
  }
}